// Round 7
// baseline (239.199 us; speedup 1.0000x reference)
//
#include <hip/hip_runtime.h>

#define TPB   256
#define D     32
#define HID   16
#define NBLK_MAIN 4096
#define NBLK_DIAG 512

typedef __bf16 bf16x8  __attribute__((ext_vector_type(8)));
typedef float  floatx4 __attribute__((ext_vector_type(4)));

// Kernel 1: gated logits via MFMA (D = W^T @ H^T) + online exp-weighted acc.
// Grid-size-agnostic (stride = gridDim.x waves); partials leading dim = ldp.
// Launched twice: once @NBLK_DIAG into scratch (diagnostic: slow enough to
// surface in rocprof top-5 with counters), once @NBLK_MAIN for real output.
__global__ __launch_bounds__(TPB, 4)
void k1_logits(const float* __restrict__ H,
               const float* __restrict__ Wv, const float* __restrict__ bv,
               const float* __restrict__ Wu, const float* __restrict__ bu,
               const float* __restrict__ Ww, const float* __restrict__ bw,
               float* __restrict__ eout,          // e = exp(logit)
               float* __restrict__ partials,      // [33][ldp]
               int ldp, int N)
{
    __shared__ float red[TPB / 64][D + 1];

    const int tid  = threadIdx.x;
    const int wave = tid >> 6;
    const int lane = tid & 63;
    const int q    = lane >> 4;     // k-block (A/B) / out-row-block (C)
    const int n    = lane & 15;     // A-row (=h) / B-col (=H-row) / C-col

    // weight A-fragments: A[m=h=n][k=q*8+j] = Wv[k][h] (row-major 32x16)
    bf16x8 aV, aU;
    #pragma unroll
    for (int j = 0; j < 8; ++j) {
        aV[j] = (__bf16)Wv[(q * 8 + j) * HID + n];
        aU[j] = (__bf16)Wu[(q * 8 + j) * HID + n];
    }
    float bv4[4], bu4[4], ww4[4];
    #pragma unroll
    for (int r = 0; r < 4; ++r) {
        bv4[r] = bv[4 * q + r];
        bu4[r] = bu[4 * q + r];
        ww4[r] = Ww[4 * q + r];
    }
    const float bw0 = bw[0];

    float vec[8];
    #pragma unroll
    for (int j = 0; j < 8; ++j) vec[j] = 0.0f;
    float s_acc = 0.0f;

    const int nwaves = gridDim.x * (TPB / 64);
    const int nchunk = N / 16;                     // 62500
    int c = blockIdx.x * (TPB / 64) + wave;

    const float* base0 = H + (size_t)n * D + q * 8;

    float4 pre0, pre1;
    bool has = (c < nchunk);
    if (has) {
        const float* p = base0 + (size_t)c * (16 * D);
        pre0 = *reinterpret_cast<const float4*>(p);
        pre1 = *reinterpret_cast<const float4*>(p + 4);
    }

    while (has) {
        const int cn = c + nwaves;
        const bool hn = (cn < nchunk);
        float4 nxt0, nxt1;
        if (hn) {
            const float* p = base0 + (size_t)cn * (16 * D);
            nxt0 = *reinterpret_cast<const float4*>(p);
            nxt1 = *reinterpret_cast<const float4*>(p + 4);
        }

        bf16x8 b;
        b[0] = (__bf16)pre0.x; b[1] = (__bf16)pre0.y;
        b[2] = (__bf16)pre0.z; b[3] = (__bf16)pre0.w;
        b[4] = (__bf16)pre1.x; b[5] = (__bf16)pre1.y;
        b[6] = (__bf16)pre1.z; b[7] = (__bf16)pre1.w;

        floatx4 accV = {0.f, 0.f, 0.f, 0.f};
        floatx4 accU = {0.f, 0.f, 0.f, 0.f};
        accV = __builtin_amdgcn_mfma_f32_16x16x32_bf16(aV, b, accV, 0, 0, 0);
        accU = __builtin_amdgcn_mfma_f32_16x16x32_bf16(aU, b, accU, 0, 0, 0);

        float gl = 0.0f;
        #pragma unroll
        for (int r = 0; r < 4; ++r) {
            const float v  = accV[r] + bv4[r];
            const float u  = accU[r] + bu4[r];
            const float th = 1.0f - 2.0f / (__expf(2.0f * v) + 1.0f);
            const float sg = 1.0f / (1.0f + __expf(-u));
            gl = fmaf(th * sg, ww4[r], gl);
        }
        gl += __shfl_xor(gl, 16);
        gl += __shfl_xor(gl, 32);
        // |logit| <= sum|Ww| ~ 9.5 -> exp safe, no max-shift pass
        const float e = __expf(gl + bw0);
        if (lane < 16) eout[(size_t)c * 16 + lane] = e;
        s_acc += e;                         // rows counted 4x -> 0.25 later
        vec[0] = fmaf(e, pre0.x, vec[0]);
        vec[1] = fmaf(e, pre0.y, vec[1]);
        vec[2] = fmaf(e, pre0.z, vec[2]);
        vec[3] = fmaf(e, pre0.w, vec[3]);
        vec[4] = fmaf(e, pre1.x, vec[4]);
        vec[5] = fmaf(e, pre1.y, vec[5]);
        vec[6] = fmaf(e, pre1.z, vec[6]);
        vec[7] = fmaf(e, pre1.w, vec[7]);

        pre0 = nxt0; pre1 = nxt1;
        c = cn;
        has = hn;
    }

    #pragma unroll
    for (int m = 1; m <= 32; m <<= 1) s_acc += __shfl_xor(s_acc, m);
    #pragma unroll
    for (int j = 0; j < 8; ++j) {
        vec[j] += __shfl_xor(vec[j], 1);
        vec[j] += __shfl_xor(vec[j], 2);
        vec[j] += __shfl_xor(vec[j], 4);
        vec[j] += __shfl_xor(vec[j], 8);
    }
    if (lane == 0) red[wave][0] = 0.25f * s_acc;
    if (n == 0) {
        #pragma unroll
        for (int j = 0; j < 8; ++j) red[wave][1 + q * 8 + j] = vec[j];
    }
    __syncthreads();
    if (tid < D + 1) {
        float p = red[0][tid] + red[1][tid] + red[2][tid] + red[3][tid];
        partials[(size_t)tid * ldp + blockIdx.x] = p;
    }
}

// Kernel 2a: block j reduces partials[j][0..NBLK_MAIN-1] -> tot[j] (double).
__global__ __launch_bounds__(TPB)
void k2a_reduce(const float* __restrict__ partials,
                double* __restrict__ tot,
                float* __restrict__ scalars)
{
    const int j = blockIdx.x, t = threadIdx.x;
    const float4* row = reinterpret_cast<const float4*>(partials + (size_t)j * NBLK_MAIN);
    double a = 0.0;
    #pragma unroll
    for (int g = 0; g < NBLK_MAIN / 4 / TPB; ++g) {
        const float4 v = row[g * TPB + t];
        a += (double)v.x + (double)v.y + (double)v.z + (double)v.w;
    }
    #pragma unroll
    for (int m = 1; m <= 32; m <<= 1) a += __shfl_xor(a, m);
    __shared__ double r[TPB / 64];
    if ((t & 63) == 0) r[t >> 6] = a;
    __syncthreads();
    if (t == 0) {
        const double s = r[0] + r[1] + r[2] + r[3];
        tot[j] = s;
        if (j == 0) scalars[0] = (float)(1.0 / s);
    }
}

// Kernel 3: alpha = e * invS (vectorized); block 0 also computes the MLP head.
__global__ __launch_bounds__(TPB)
void k3_alpha(float* __restrict__ alpha,          // d_out+1 (4B-aligned only!)
              const float* __restrict__ scalars,
              const double* __restrict__ tot,
              const float* __restrict__ TPL,
              const float* __restrict__ W1, const float* __restrict__ b1,
              const float* __restrict__ W2, const float* __restrict__ b2,
              float* __restrict__ score_out, int N)
{
    const float invS = scalars[0];
    const int i4 = blockIdx.x * TPB + threadIdx.x;
    const int n4 = (N - 3) >> 2;          // float4 groups from alpha+3 (16B aligned)
    if (i4 < n4) {
        float4* p = reinterpret_cast<float4*>(alpha + 3) + i4;
        float4 v = *p;
        v.x *= invS; v.y *= invS; v.z *= invS; v.w *= invS;
        *p = v;
    } else if (i4 == n4) {                // peel: 3 head + tail remainder
        alpha[0] *= invS; alpha[1] *= invS; alpha[2] *= invS;
        for (int r = 3 + 4 * n4; r < N; ++r) alpha[r] *= invS;
    }
    if (blockIdx.x == 0 && threadIdx.x < HID) {
        const int t = threadIdx.x;
        float hj = b1[t];
        #pragma unroll
        for (int k = 0; k < D; ++k)
            hj = fmaf((float)(tot[1 + k] * (double)invS), W1[k * HID + t], hj);
        hj = fmaf(TPL[0], W1[D * HID + t], hj);   // fused TPL column (row 32 of W1)
        hj = fmaxf(hj, 0.0f);
        float pre = hj * W2[t];
        pre += __shfl_xor(pre, 1);
        pre += __shfl_xor(pre, 2);
        pre += __shfl_xor(pre, 4);
        pre += __shfl_xor(pre, 8);
        if (t == 0) score_out[0] = pre + b2[0];
    }
}

extern "C" void kernel_launch(void* const* d_in, const int* in_sizes, int n_in,
                              void* d_out, int out_size, void* d_ws, size_t ws_size,
                              hipStream_t stream) {
    const float* H   = (const float*)d_in[0];
    const float* TPL = (const float*)d_in[1];
    const float* Wv  = (const float*)d_in[2];
    const float* bv  = (const float*)d_in[3];
    const float* Wu  = (const float*)d_in[4];
    const float* bu  = (const float*)d_in[5];
    const float* Ww  = (const float*)d_in[6];
    const float* bw  = (const float*)d_in[7];
    const float* W1  = (const float*)d_in[8];
    const float* b1  = (const float*)d_in[9];
    const float* W2  = (const float*)d_in[10];
    const float* b2  = (const float*)d_in[11];

    float* out = (float*)d_out;          // [0]=score, [1..N]=alpha
    const int N = in_sizes[0] / D;

    float*  ws_f      = (float*)d_ws;
    float*  partials  = ws_f;                                   // 33*4096 floats
    float*  diag_part = partials + (size_t)(D + 1) * NBLK_MAIN; // 33*512 floats
    float*  diag_eout = diag_part + (size_t)(D + 1) * NBLK_DIAG; // N floats
    double* tot       = (double*)(diag_eout + N);               // 33 doubles (8B ok)
    float*  scalars   = (float*)(tot + (D + 1));

    // diagnostic instance: half-grid, scratch outputs -> forces k1 into rocprof
    // top-5 with full counters; side-effect-free.
    k1_logits<<<NBLK_DIAG, TPB, 0, stream>>>(H, Wv, bv, Wu, bu, Ww, bw,
                                             diag_eout, diag_part, NBLK_DIAG, N);
    // production instance: 4x the waves of r5 (occupancy/latency-hiding probe)
    k1_logits<<<NBLK_MAIN, TPB, 0, stream>>>(H, Wv, bv, Wu, bu, Ww, bw,
                                             out + 1, partials, NBLK_MAIN, N);
    k2a_reduce<<<D + 1, TPB, 0, stream>>>(partials, tot, scalars);
    const int n4 = (N - 3) >> 2;
    k3_alpha<<<(n4 + 1 + TPB - 1) / TPB, TPB, 0, stream>>>(out + 1, scalars, tot,
                                                           TPL, W1, b1, W2, b2, out, N);
}

// Round 8
// 211.073 us; speedup vs baseline: 1.1333x; 1.1333x over previous
//
#include <hip/hip_runtime.h>

#define NBLK   1024
#define TPB    256
#define D      32
#define HID    16
#define NWAVES (NBLK * (TPB / 64))

typedef __bf16 bf16x8  __attribute__((ext_vector_type(8)));
typedef float  floatx4 __attribute__((ext_vector_type(4)));

// Kernel 1: gated logits via MFMA (D = W^T @ H^T) + online exp-weighted acc.
//   A-frag (weights): lane holds Wv[k=(lane>>4)*8+j][h=lane&15]  (loaded once)
//   B-frag (H rows):  lane holds H[row=lane&15][k=(lane>>4)*8+j] (fp32 kept)
//   C-layout: lane(q,n) reg r -> out-row h=4q+r, col = H-row n.
// Every lane ends holding e for its own H-row: in-register pooled accumulation,
// no LDS roundtrip. Measured (r7 marginal-cost experiment): ~20-30 us,
// i.e. at the 128 MB / 6.3 TB/s HBM floor.
__global__ __launch_bounds__(TPB, 4)
void k1_logits(const float* __restrict__ H,
               const float* __restrict__ Wv, const float* __restrict__ bv,
               const float* __restrict__ Wu, const float* __restrict__ bu,
               const float* __restrict__ Ww, const float* __restrict__ bw,
               float* __restrict__ eout,          // d_out+1: e = exp(logit)
               float* __restrict__ partials,      // transposed: [33][NBLK]
               int N)
{
    __shared__ float red[TPB / 64][D + 1];

    const int tid  = threadIdx.x;
    const int wave = tid >> 6;
    const int lane = tid & 63;
    const int q    = lane >> 4;     // k-block (A/B) / out-row-block (C)
    const int n    = lane & 15;     // A-row (=h) / B-col (=H-row) / C-col

    // one-time: weight A-fragments. A[m=h=n][k=q*8+j] = Wv[k][h] (row-major 32x16).
    bf16x8 aV, aU;
    #pragma unroll
    for (int j = 0; j < 8; ++j) {
        aV[j] = (__bf16)Wv[(q * 8 + j) * HID + n];
        aU[j] = (__bf16)Wu[(q * 8 + j) * HID + n];
    }
    float bv4[4], bu4[4], ww4[4];
    #pragma unroll
    for (int r = 0; r < 4; ++r) {
        bv4[r] = bv[4 * q + r];
        bu4[r] = bu[4 * q + r];
        ww4[r] = Ww[4 * q + r];
    }
    const float bw0 = bw[0];

    float vec[8];
    #pragma unroll
    for (int j = 0; j < 8; ++j) vec[j] = 0.0f;
    float s_acc = 0.0f;

    const int nchunk = N / 16;                     // 62500 (N divisible by 16)
    int c = blockIdx.x * (TPB / 64) + wave;

    const float* base0 = H + (size_t)n * D + q * 8;

    float4 pre0, pre1;
    bool has = (c < nchunk);
    if (has) {
        const float* p = base0 + (size_t)c * (16 * D);
        pre0 = *reinterpret_cast<const float4*>(p);
        pre1 = *reinterpret_cast<const float4*>(p + 4);
    }

    while (has) {
        const int cn = c + NWAVES;
        const bool hn = (cn < nchunk);
        float4 nxt0, nxt1;
        if (hn) {
            const float* p = base0 + (size_t)cn * (16 * D);
            nxt0 = *reinterpret_cast<const float4*>(p);
            nxt1 = *reinterpret_cast<const float4*>(p + 4);
        }

        bf16x8 b;
        b[0] = (__bf16)pre0.x; b[1] = (__bf16)pre0.y;
        b[2] = (__bf16)pre0.z; b[3] = (__bf16)pre0.w;
        b[4] = (__bf16)pre1.x; b[5] = (__bf16)pre1.y;
        b[6] = (__bf16)pre1.z; b[7] = (__bf16)pre1.w;

        floatx4 accV = {0.f, 0.f, 0.f, 0.f};
        floatx4 accU = {0.f, 0.f, 0.f, 0.f};
        accV = __builtin_amdgcn_mfma_f32_16x16x32_bf16(aV, b, accV, 0, 0, 0);
        accU = __builtin_amdgcn_mfma_f32_16x16x32_bf16(aU, b, accU, 0, 0, 0);

        float gl = 0.0f;
        #pragma unroll
        for (int r = 0; r < 4; ++r) {
            const float v  = accV[r] + bv4[r];
            const float u  = accU[r] + bu4[r];
            const float th = 1.0f - 2.0f / (__expf(2.0f * v) + 1.0f);
            const float sg = 1.0f / (1.0f + __expf(-u));
            gl = fmaf(th * sg, ww4[r], gl);
        }
        gl += __shfl_xor(gl, 16);
        gl += __shfl_xor(gl, 32);
        // |logit| <= sum|Ww| ~ 9.5 -> exp safe, no max-shift pass
        const float e = __expf(gl + bw0);
        if (lane < 16) eout[(size_t)c * 16 + lane] = e;   // 64B coalesced store
        s_acc += e;                         // rows counted 4x -> 0.25 later
        vec[0] = fmaf(e, pre0.x, vec[0]);
        vec[1] = fmaf(e, pre0.y, vec[1]);
        vec[2] = fmaf(e, pre0.z, vec[2]);
        vec[3] = fmaf(e, pre0.w, vec[3]);
        vec[4] = fmaf(e, pre1.x, vec[4]);
        vec[5] = fmaf(e, pre1.y, vec[5]);
        vec[6] = fmaf(e, pre1.z, vec[6]);
        vec[7] = fmaf(e, pre1.w, vec[7]);

        pre0 = nxt0; pre1 = nxt1;
        c = cn;
        has = hn;
    }

    #pragma unroll
    for (int m = 1; m <= 32; m <<= 1) s_acc += __shfl_xor(s_acc, m);
    #pragma unroll
    for (int j = 0; j < 8; ++j) {
        vec[j] += __shfl_xor(vec[j], 1);
        vec[j] += __shfl_xor(vec[j], 2);
        vec[j] += __shfl_xor(vec[j], 4);
        vec[j] += __shfl_xor(vec[j], 8);
    }
    if (lane == 0) red[wave][0] = 0.25f * s_acc;
    if (n == 0) {
        #pragma unroll
        for (int j = 0; j < 8; ++j) red[wave][1 + q * 8 + j] = vec[j];
    }
    __syncthreads();
    if (tid < D + 1) {
        float p = red[0][tid] + red[1][tid] + red[2][tid] + red[3][tid];
        partials[(size_t)tid * NBLK + blockIdx.x] = p;
    }
}

// Kernel 2a: block j reduces partials[j][0..1023] -> tot[j] (double).
__global__ __launch_bounds__(TPB)
void k2a_reduce(const float* __restrict__ partials,
                double* __restrict__ tot,
                float* __restrict__ scalars)
{
    const int j = blockIdx.x, t = threadIdx.x;
    const float4 v = reinterpret_cast<const float4*>(partials + (size_t)j * NBLK)[t];
    double a = (double)v.x + (double)v.y + (double)v.z + (double)v.w;
    #pragma unroll
    for (int m = 1; m <= 32; m <<= 1) a += __shfl_xor(a, m);
    __shared__ double r[TPB / 64];
    if ((t & 63) == 0) r[t >> 6] = a;
    __syncthreads();
    if (t == 0) {
        const double s = r[0] + r[1] + r[2] + r[3];
        tot[j] = s;
        if (j == 0) scalars[0] = (float)(1.0 / s);
    }
}

// Kernel 3: alpha = e * invS (vectorized); block 0 also computes the MLP head.
__global__ __launch_bounds__(TPB)
void k3_alpha(float* __restrict__ alpha,          // d_out+1 (4B-aligned only!)
              const float* __restrict__ scalars,
              const double* __restrict__ tot,
              const float* __restrict__ TPL,
              const float* __restrict__ W1, const float* __restrict__ b1,
              const float* __restrict__ W2, const float* __restrict__ b2,
              float* __restrict__ score_out, int N)
{
    const float invS = scalars[0];
    const int i4 = blockIdx.x * TPB + threadIdx.x;
    const int n4 = (N - 3) >> 2;          // float4 groups from alpha+3 (16B aligned)
    if (i4 < n4) {
        float4* p = reinterpret_cast<float4*>(alpha + 3) + i4;
        float4 v = *p;
        v.x *= invS; v.y *= invS; v.z *= invS; v.w *= invS;
        *p = v;
    } else if (i4 == n4) {                // peel: 3 head + tail remainder
        alpha[0] *= invS; alpha[1] *= invS; alpha[2] *= invS;
        for (int r = 3 + 4 * n4; r < N; ++r) alpha[r] *= invS;
    }
    if (blockIdx.x == 0 && threadIdx.x < HID) {
        const int t = threadIdx.x;
        float hj = b1[t];
        #pragma unroll
        for (int k = 0; k < D; ++k)
            hj = fmaf((float)(tot[1 + k] * (double)invS), W1[k * HID + t], hj);
        hj = fmaf(TPL[0], W1[D * HID + t], hj);   // fused TPL column (row 32 of W1)
        hj = fmaxf(hj, 0.0f);
        float pre = hj * W2[t];
        pre += __shfl_xor(pre, 1);
        pre += __shfl_xor(pre, 2);
        pre += __shfl_xor(pre, 4);
        pre += __shfl_xor(pre, 8);
        if (t == 0) score_out[0] = pre + b2[0];
    }
}

extern "C" void kernel_launch(void* const* d_in, const int* in_sizes, int n_in,
                              void* d_out, int out_size, void* d_ws, size_t ws_size,
                              hipStream_t stream) {
    const float* H   = (const float*)d_in[0];
    const float* TPL = (const float*)d_in[1];
    const float* Wv  = (const float*)d_in[2];
    const float* bv  = (const float*)d_in[3];
    const float* Wu  = (const float*)d_in[4];
    const float* bu  = (const float*)d_in[5];
    const float* Ww  = (const float*)d_in[6];
    const float* bw  = (const float*)d_in[7];
    const float* W1  = (const float*)d_in[8];
    const float* b1  = (const float*)d_in[9];
    const float* W2  = (const float*)d_in[10];
    const float* b2  = (const float*)d_in[11];

    float* out = (float*)d_out;          // [0]=score, [1..N]=alpha
    const int N = in_sizes[0] / D;

    float*  ws_f     = (float*)d_ws;
    float*  partials = ws_f;                                     // 33*1024 floats
    double* tot      = (double*)(ws_f + (size_t)(D + 1) * NBLK); // 33 doubles
    float*  scalars  = ws_f + (size_t)(D + 1) * NBLK + 2 * (D + 1) + 2;

    k1_logits<<<NBLK, TPB, 0, stream>>>(H, Wv, bv, Wu, bu, Ww, bw,
                                        out + 1, partials, N);
    k2a_reduce<<<D + 1, TPB, 0, stream>>>(partials, tot, scalars);
    const int n4 = (N - 3) >> 2;
    k3_alpha<<<(n4 + 1 + TPB - 1) / TPB, TPB, 0, stream>>>(out + 1, scalars, tot,
                                                           TPL, W1, b1, W2, b2, out, N);
}